// Round 1
// baseline (255.314 us; speedup 1.0000x reference)
//
#include <hip/hip_runtime.h>
#include <cstdint>
#include <cstddef>

typedef float f32x4 __attribute__((ext_vector_type(4)));
typedef short s16x8 __attribute__((ext_vector_type(8)));
typedef short s16x4 __attribute__((ext_vector_type(4)));

#define MFMA_BF16(a, b, c) __builtin_amdgcn_mfma_f32_16x16x32_bf16((a), (b), (c), 0, 0, 0)

// async global->LDS DMA, 16B/lane: lands at ldsbase + lane*16 (wave-uniform base)
#define GLD16(g, l)                                                            \
  __builtin_amdgcn_global_load_lds(                                            \
      (const __attribute__((address_space(1))) void*)(g),                      \
      (__attribute__((address_space(3))) void*)(l), 16, 0, 0)

__device__ __forceinline__ unsigned short f2bf(float f) {
  unsigned int u = __float_as_uint(f);
  u += 0x7FFFu + ((u >> 16) & 1u);
  return (unsigned short)(u >> 16);
}

__device__ __forceinline__ s16x8 cvt8(const float* __restrict__ src) {
  const float4 f0 = *(const float4*)src;
  const float4 f1 = *(const float4*)(src + 4);
  s16x8 h;
  h[0] = (short)f2bf(f0.x); h[1] = (short)f2bf(f0.y);
  h[2] = (short)f2bf(f0.z); h[3] = (short)f2bf(f0.w);
  h[4] = (short)f2bf(f1.x); h[5] = (short)f2bf(f1.y);
  h[6] = (short)f2bf(f1.z); h[7] = (short)f2bf(f1.w);
  return h;
}

// ---------------------------------------------------------------------------
// cvt_bf16: x -> xb, w_qkv[0:1024] -> wb (V-proj rows dead: reference builds
// v2 from k), w_out -> wob. Memory-bound one-shot.
// ---------------------------------------------------------------------------
#define XN 16777216   // 4*8192*512
#define WQN 524288    // 1024*512
__global__ __launch_bounds__(256)
void cvt_bf16(const float* __restrict__ x, const float* __restrict__ wqkv,
              const float* __restrict__ wout, unsigned short* __restrict__ xb,
              unsigned short* __restrict__ wb, unsigned short* __restrict__ wob) {
  const size_t i = (size_t)(blockIdx.x * 256 + threadIdx.x) * 8;
  const float* src;
  unsigned short* dst;
  if (i < XN) { src = x + i; dst = xb + i; }
  else if (i < XN + WQN) { src = wqkv + (i - XN); dst = wb + (i - XN); }
  else { src = wout + (i - XN - WQN); dst = wob + (i - XN - WQN); }
  *(s16x8*)dst = cvt8(src);
}

// ---------------------------------------------------------------------------
// gemm_qk: [Q|K] = xb @ wb^T. M=32768 N=1024 K=512. m97 structure, GLD16 both
// operands, XOR-swizzled LDS. SWAPPED staging (W->As, x->Bs, block-uniform
// pointer select): D comes out transposed -> packed 8B Q/K stores.
// XCD-aware map: each XCD runs all 8 n-tiles of one m-tile consecutively.
// ---------------------------------------------------------------------------
__global__ __launch_bounds__(256)
void gemm_qk(const unsigned short* __restrict__ xb, const unsigned short* __restrict__ wb,
             unsigned short* __restrict__ Q, unsigned short* __restrict__ K) {
  __shared__ unsigned short As[128 * 64];  // W tile
  __shared__ unsigned short Bs[128 * 64];  // x tile
  const int t = threadIdx.x, lane = t & 63, wid = t >> 6;
  const int wm = wid >> 1, wn = wid & 1;
  const int nl = lane & 15, quad = lane >> 4;
  const int sub = lane >> 3, lblk = (lane & 7) ^ sub;
  const int l = blockIdx.x;
  const int xcd = l & 7, g = l >> 3;
  const int mt = (g >> 3) * 8 + xcd, nt = g & 7;
  const int m0 = mt * 128, n0 = nt * 128;

  const f32x4 zero = {0.f, 0.f, 0.f, 0.f};
  f32x4 acc[4][4];
#pragma unroll
  for (int i = 0; i < 4; ++i)
#pragma unroll
    for (int j = 0; j < 4; ++j) acc[i][j] = zero;

  const unsigned short* gX = xb + (size_t)(m0 + wid * 32 + sub) * 512 + lblk * 8;
  const unsigned short* gW = wb + (size_t)(n0 + wid * 32 + sub) * 512 + lblk * 8;

  for (int kc = 0; kc < 512; kc += 64) {
#pragma unroll
    for (int ii = 0; ii < 4; ++ii) {
      GLD16(gW + kc + (size_t)(ii * 8) * 512, &As[(wid * 32 + ii * 8) * 64]);
      GLD16(gX + kc + (size_t)(ii * 8) * 512, &Bs[(wid * 32 + ii * 8) * 64]);
    }
    __syncthreads();
#pragma unroll
    for (int ks = 0; ks < 2; ++ks) {
      s16x8 af[4], bf[4];
#pragma unroll
      for (int i = 0; i < 4; ++i)
        af[i] = *(const s16x8*)&As[(wm * 64 + i * 16 + nl) * 64 +
                                   (((ks * 4 + quad) ^ (nl & 7)) * 8)];
#pragma unroll
      for (int j = 0; j < 4; ++j)
        bf[j] = *(const s16x8*)&Bs[(wn * 64 + j * 16 + nl) * 64 +
                                   (((ks * 4 + quad) ^ (nl & 7)) * 8)];
#pragma unroll
      for (int i = 0; i < 4; ++i)
#pragma unroll
        for (int j = 0; j < 4; ++j) acc[i][j] = MFMA_BF16(af[i], bf[j], acc[i][j]);
    }
    __syncthreads();
  }
  // D rows = W-feature n (contiguous in reg r), cols = seq m -> packed stores
#pragma unroll
  for (int i = 0; i < 4; ++i) {
    const int n = n0 + wm * 64 + i * 16 + quad * 4;
    unsigned short* base = (n < 512 ? Q : K);
    const int nn = n & 511;
#pragma unroll
    for (int j = 0; j < 4; ++j) {
      const int m = m0 + wn * 64 + j * 16 + nl;
      s16x4 h;
#pragma unroll
      for (int r = 0; r < 4; ++r) h[r] = (short)f2bf(acc[i][j][r]);
      *(s16x4*)&base[(size_t)m * 512 + nn] = h;
    }
  }
}

// ---------------------------------------------------------------------------
// gemm_kwt: KWT[b][o][seq] = (K @ wob^T)^T — output projection hoisted before
// attention (out@w_out^T == P@(K2@w_out^T)). Normal operand order: D rows =
// seq (contiguous in r) -> packed 8B transposed stores. XCD-swizzled.
// ---------------------------------------------------------------------------
__global__ __launch_bounds__(256)
void gemm_kwt(const unsigned short* __restrict__ K, const unsigned short* __restrict__ wob,
              unsigned short* __restrict__ KWT) {
  __shared__ unsigned short As[128 * 64];
  __shared__ unsigned short Bs[128 * 64];
  const int t = threadIdx.x, lane = t & 63, wid = t >> 6;
  const int wm = wid >> 1, wn = wid & 1;
  const int nl = lane & 15, quad = lane >> 4;
  const int sub = lane >> 3, lblk = (lane & 7) ^ sub;
  const int l = blockIdx.x;
  const int xcd = l & 7, g = l >> 3;
  const int mt = (g >> 2) * 8 + xcd, nt = g & 3;
  const int m0 = mt * 128, n0 = nt * 128;

  const f32x4 zero = {0.f, 0.f, 0.f, 0.f};
  f32x4 acc[4][4];
#pragma unroll
  for (int i = 0; i < 4; ++i)
#pragma unroll
    for (int j = 0; j < 4; ++j) acc[i][j] = zero;

  const unsigned short* gA = K + (size_t)(m0 + wid * 32 + sub) * 512 + lblk * 8;
  const unsigned short* gB = wob + (size_t)(n0 + wid * 32 + sub) * 512 + lblk * 8;

  for (int kc = 0; kc < 512; kc += 64) {
#pragma unroll
    for (int ii = 0; ii < 4; ++ii) {
      GLD16(gA + kc + (size_t)(ii * 8) * 512, &As[(wid * 32 + ii * 8) * 64]);
      GLD16(gB + kc + (size_t)(ii * 8) * 512, &Bs[(wid * 32 + ii * 8) * 64]);
    }
    __syncthreads();
#pragma unroll
    for (int ks = 0; ks < 2; ++ks) {
      s16x8 af[4], bf[4];
#pragma unroll
      for (int i = 0; i < 4; ++i)
        af[i] = *(const s16x8*)&As[(wm * 64 + i * 16 + nl) * 64 +
                                   (((ks * 4 + quad) ^ (nl & 7)) * 8)];
#pragma unroll
      for (int j = 0; j < 4; ++j)
        bf[j] = *(const s16x8*)&Bs[(wn * 64 + j * 16 + nl) * 64 +
                                   (((ks * 4 + quad) ^ (nl & 7)) * 8)];
#pragma unroll
      for (int i = 0; i < 4; ++i)
#pragma unroll
        for (int j = 0; j < 4; ++j) acc[i][j] = MFMA_BF16(af[i], bf[j], acc[i][j]);
    }
    __syncthreads();
  }
#pragma unroll
  for (int i = 0; i < 4; ++i) {
    const int ms = m0 + wm * 64 + i * 16 + quad * 4;
    const int b = ms >> 13, ns = ms & 8191;
#pragma unroll
    for (int j = 0; j < 4; ++j) {
      const int o = n0 + wn * 64 + j * 16 + nl;
      s16x4 h;
#pragma unroll
      for (int r = 0; r < 4; ++r) h[r] = (short)f2bf(acc[i][j][r]);
      *(s16x4*)&KWT[(size_t)(b * 512 + o) * 8192 + ns] = h;
    }
  }
}

// ---------------------------------------------------------------------------
// attn64 v2: one block = 64 Q-rows of one window (2 blocks/window, grid 512).
// ALL operand staging removed: Q/K2/KWT slices are L2-resident (paired-XCD
// swizzle keeps both half-window blocks + their shared K2/KWT on one XCD),
// and the 16x16x32 A/B fragment layout (row = i*16+nl, 8 contiguous k-elems
// at (ks*4+quad)*8) is directly loadable from row-major global memory as
// fully-coalesced dwordx4 (quad spans a 64B line). The old LDS path's XOR
// swizzle cancels between write and read, so element mapping is identical.
// Barriers: 56 -> 3 (softmax max, softmax sum, P publish). Only P goes
// through LDS (genuine relayout for the PV A-operand), conflict-free swizzle.
// ---------------------------------------------------------------------------
__global__ __launch_bounds__(256)
void attn64(const unsigned short* __restrict__ Q, const unsigned short* __restrict__ K,
            const unsigned short* __restrict__ KWT, const float* __restrict__ bias,
            float* __restrict__ out) {
  __shared__ unsigned short Ps[64 * 256];  // 32KB: P, swizzled row-major
  __shared__ float redm[256];
  __shared__ float reds[256];
  const int t = threadIdx.x, lane = t & 63, wid = t >> 6;
  const int wn = wid;  // 4 waves split the 256 sim cols
  const int nl = lane & 15, quad = lane >> 4;
  // paired-XCD decode: bx = g*16 + half*8 + xcd
  const int bx = blockIdx.x;
  const int xcd = bx & 7, half = (bx >> 3) & 1, g = bx >> 4;
  const int wb = g * 8 + xcd, b = wb >> 6, w = wb & 63;

  const f32x4 zero = {0.f, 0.f, 0.f, 0.f};
  f32x4 acc[4][4];
#pragma unroll
  for (int i = 0; i < 4; ++i)
#pragma unroll
    for (int j = 0; j < 4; ++j) acc[i][j] = zero;

  const unsigned short* Qb = Q + (size_t)(b * 8192 + w * 128 + half * 64) * 512;
  const unsigned short* Kb = K + (size_t)(b * 8192) * 512;

  // per-lane fragment row pointers (constant over the K loop)
  const unsigned short* qptr[4];
  const unsigned short* kptr[4];
#pragma unroll
  for (int i = 0; i < 4; ++i) qptr[i] = Qb + (size_t)(i * 16 + nl) * 512;
#pragma unroll
  for (int j = 0; j < 4; ++j) {
    int seq = w * 128 - 128 + wn * 64 + j * 16 + nl;
    if (seq < 0) seq = 0;  // window 0: finite garbage, neutralized pre-softmax
    kptr[j] = Kb + (size_t)seq * 512;
  }

  // phase 1: sim = Q . K2^T, fragments direct from L2, no barriers
#pragma unroll 2
  for (int kc = 0; kc < 512; kc += 64) {
#pragma unroll
    for (int ks = 0; ks < 2; ++ks) {
      const int off = kc + (ks * 4 + quad) * 8;
      s16x8 af[4], bf[4];
#pragma unroll
      for (int i = 0; i < 4; ++i) af[i] = *(const s16x8*)(qptr[i] + off);
#pragma unroll
      for (int j = 0; j < 4; ++j) bf[j] = *(const s16x8*)(kptr[j] + off);
      __builtin_amdgcn_s_setprio(1);
#pragma unroll
      for (int i = 0; i < 4; ++i)
#pragma unroll
        for (int j = 0; j < 4; ++j) acc[i][j] = MFMA_BF16(af[i], bf[j], acc[i][j]);
      __builtin_amdgcn_s_setprio(0);
    }
  }

  const float scale = 0.04419417382415922f;  // 512^-0.5
  float rmax[4][4];
#pragma unroll
  for (int i = 0; i < 4; ++i) {
#pragma unroll
    for (int r = 0; r < 4; ++r) {
      const int qrow = half * 64 + i * 16 + quad * 4 + r;  // within-window row
      float mx = -3.4e38f;
#pragma unroll
      for (int j = 0; j < 4; ++j) {
        const int col = wn * 64 + j * 16 + nl;
        float v = acc[i][j][r] * scale;
        if (col >= 128 && col - 128 > qrow) v = -3.0e38f;  // causal mask
        if (w == 0 && col < 128) v = 0.0f;                 // zero bucket: sim=0
        acc[i][j][r] = v;
        mx = fmaxf(mx, v);
      }
      rmax[i][r] = mx;
    }
  }
#pragma unroll
  for (int off = 1; off < 16; off <<= 1)
#pragma unroll
    for (int i = 0; i < 4; ++i)
#pragma unroll
      for (int r = 0; r < 4; ++r)
        rmax[i][r] = fmaxf(rmax[i][r], __shfl_xor(rmax[i][r], off, 64));
  if (nl == 0) {
#pragma unroll
    for (int i = 0; i < 4; ++i)
#pragma unroll
      for (int r = 0; r < 4; ++r)
        redm[(i * 16 + quad * 4 + r) * 4 + wn] = rmax[i][r];
  }
  __syncthreads();
  float rsum[4][4];
#pragma unroll
  for (int i = 0; i < 4; ++i) {
#pragma unroll
    for (int r = 0; r < 4; ++r) {
      const f32x4 mv = *(const f32x4*)&redm[(i * 16 + quad * 4 + r) * 4];
      const float m = fmaxf(fmaxf(mv[0], mv[1]), fmaxf(mv[2], mv[3]));
      float s = 0.f;
#pragma unroll
      for (int j = 0; j < 4; ++j) {
        const float p = __expf(acc[i][j][r] - m);
        acc[i][j][r] = p;
        s += p;
      }
      rsum[i][r] = s;
    }
  }
#pragma unroll
  for (int off = 1; off < 16; off <<= 1)
#pragma unroll
    for (int i = 0; i < 4; ++i)
#pragma unroll
      for (int r = 0; r < 4; ++r) rsum[i][r] += __shfl_xor(rsum[i][r], off, 64);
  if (nl == 0) {
#pragma unroll
    for (int i = 0; i < 4; ++i)
#pragma unroll
      for (int r = 0; r < 4; ++r)
        reds[(i * 16 + quad * 4 + r) * 4 + wn] = rsum[i][r];
  }
  __syncthreads();
  // normalize, write P -> LDS (swizzled row-major 64x256 bf16)
#pragma unroll
  for (int i = 0; i < 4; ++i) {
#pragma unroll
    for (int r = 0; r < 4; ++r) {
      const int row = i * 16 + quad * 4 + r;
      const f32x4 sv = *(const f32x4*)&reds[row * 4];
      const float inv = 1.0f / (sv[0] + sv[1] + sv[2] + sv[3]);
#pragma unroll
      for (int j = 0; j < 4; ++j) {
        const int col = wn * 64 + j * 16 + nl;
        float pv = acc[i][j][r] * inv;
        if (w == 0 && col < 128) pv = 0.0f;  // zero V bucket
        const int cb = col >> 3;
        Ps[row * 256 + (((cb ^ (row & 7)) << 3) | (col & 7))] = f2bf(pv);
      }
    }
  }
  __syncthreads();

  // phase 2: out(64x512) = P(64x256) @ KWT-slice^T — B fragments direct from
  // L2 (KWT slice shared with the paired block), no barriers in the loop.
  const int seqbase = w * 128 - 128;
#pragma unroll 1
  for (int och = 0; och < 4; ++och) {
    f32x4 acc2[4][2];
#pragma unroll
    for (int i = 0; i < 4; ++i)
#pragma unroll
      for (int j = 0; j < 2; ++j) acc2[i][j] = zero;
    const unsigned short* bp0 =
        KWT + (size_t)(b * 512 + och * 128 + wn * 32 + nl) * 8192;
    const unsigned short* bp1 = bp0 + (size_t)16 * 8192;
#pragma unroll
    for (int kch = 0; kch < 4; ++kch) {
#pragma unroll
      for (int ks = 0; ks < 2; ++ks) {
        int sq = seqbase + kch * 64 + (ks * 4 + quad) * 8;
        if (sq < 0) sq = 0;  // window 0: garbage seq hits zeroed P cols
        const int kb = kch * 8 + ks * 4 + quad;
        s16x8 af[4], bf[2];
#pragma unroll
        for (int i = 0; i < 4; ++i)
          af[i] = *(const s16x8*)&Ps[(i * 16 + nl) * 256 + ((kb ^ (nl & 7)) << 3)];
        bf[0] = *(const s16x8*)(bp0 + sq);
        bf[1] = *(const s16x8*)(bp1 + sq);
        __builtin_amdgcn_s_setprio(1);
#pragma unroll
        for (int i = 0; i < 4; ++i) {
          acc2[i][0] = MFMA_BF16(af[i], bf[0], acc2[i][0]);
          acc2[i][1] = MFMA_BF16(af[i], bf[1], acc2[i][1]);
        }
        __builtin_amdgcn_s_setprio(0);
      }
    }
#pragma unroll
    for (int i = 0; i < 4; ++i) {
      const int seq = w * 128 + half * 64 + i * 16 + quad * 4;
      float* dst = out + (size_t)(b * 8192 + seq) * 512;
#pragma unroll
      for (int j = 0; j < 2; ++j) {
        const int o = och * 128 + wn * 32 + j * 16 + nl;
        const float bo = bias[o];
#pragma unroll
        for (int r = 0; r < 4; ++r) dst[(size_t)r * 512 + o] = acc2[i][j][r] + bo;
      }
    }
  }
}

extern "C" void kernel_launch(void* const* d_in, const int* in_sizes, int n_in,
                              void* d_out, int out_size, void* d_ws, size_t ws_size,
                              hipStream_t stream) {
  const float* x = (const float*)d_in[0];
  const float* w_qkv = (const float*)d_in[1];
  const float* w_out = (const float*)d_in[2];
  const float* b_out = (const float*)d_in[3];
  float* out = (float*)d_out;

  char* ws = (char*)d_ws;
  // Layout (97.5 MB, within the 112 MB proven budget):
  //   Q   @  0  (32MB)
  //   K   @ 32M (32MB)
  //   xb  @ 64M (32MB)  dead after gemm_qk
  //   KWT @ 64M (32MB)  written by gemm_kwt (aliases xb)
  //   wb  @ 96M (1MB), wob @ 97M (0.5MB)
  unsigned short* Q = (unsigned short*)ws;
  unsigned short* K = (unsigned short*)(ws + (size_t)33554432);
  unsigned short* xb = (unsigned short*)(ws + (size_t)67108864);
  unsigned short* KWT = (unsigned short*)(ws + (size_t)67108864);
  unsigned short* wb = (unsigned short*)(ws + (size_t)100663296);
  unsigned short* wob = (unsigned short*)(ws + (size_t)100663296 + 1048576);

  cvt_bf16<<<dim3(8576), dim3(256), 0, stream>>>(x, w_qkv, w_out, xb, wb, wob);
  gemm_qk<<<dim3(2048), dim3(256), 0, stream>>>(xb, wb, Q, K);
  gemm_kwt<<<dim3(1024), dim3(256), 0, stream>>>(K, wob, KWT);
  attn64<<<dim3(512), dim3(256), 0, stream>>>(Q, K, KWT, b_out, out);
}